// Round 4
// baseline (2244.755 us; speedup 1.0000x reference)
//
#include <hip/hip_runtime.h>
#include <hip/hip_fp16.h>

typedef unsigned long long u64;

#define C2X 2.8853900817779268f   // 2*log2(e)
#define LOG2E 1.4426950408889634f

// ---------------- workspace layout (bytes) ----------------
#define WYS_OFF   0u          // half [32][256][256]  WY pre-scaled by 2log2e
#define PR_OFF    4194304u    // half [32][256][256]  P_r = prem @ w_r
#define PREMH_OFF 8388608u    // half [32][256][256]  premise fp16
#define HWH_OFF   12582912u   // f32  [128][32][256]  (h@w_h)*2log2e
#define WTH_OFF   16777216u   // half [256][256]      w_t
#define WTR_OFF   16908288u   // half [256][256]      W_tr = w_t @ w_r
#define ZP_OFF    17039360u   // u64 [2][32][8][256]  tagged z-partials, primary (1MB)
#define ZPS_OFF   18087936u   // u64 [2][32][8][256]  tagged z-partials, shadow  (1MB)
#define RCH_OFF   19136512u   // u64 [2][32][256]     tagged r-chunks, primary (128KB)
#define RCHS_OFF  19267584u   // u64 [2][32][256]     tagged r-chunks, shadow  (128KB)
#define CTR_OFF   19398656u   // u32 [8] per-XCD bootstrap counters
#define MEMSET_SZ (19398656u + 64u - 17039360u)

// ---------------- LDS layout (bytes) ----------------
#define PRC_OFF   0u        // [256][32] half  P_r chunk
#define WTRC_OFF  16384u    // [256][32] half  W_tr chunk
#define PREMC_OFF 32768u    // [256][32] half  prem chunk
#define WTC_OFF   49152u    // [256][32] half  w_t chunk
#define WYC_OFF   65536u    // [256][32] half  WY chunk (prescaled)
#define HWHC_OFF  81920u    // [128][32] f32
#define SCH_OFF   98304u    // 32 f32  s chunk (prescaled)
#define WACH_OFF  98432u    // 32 f32  w_alpha chunk
#define AL_OFF    98560u    // 256 f32 alpha
#define RB0_OFF   99584u    // 256 f32 r buffer 0
#define RB1_OFF   100608u   // 256 f32 r buffer 1
#define PART_OFF  102656u   // [16][32] f32
#define RED_OFF   104704u   // 16 f32
#define LDS_TOTAL 104768u   // >80KB => exactly 1 block/CU => 32 blocks/XCD guaranteed

// ---------------- prep: GEMMs ----------------
template<int MODE>
__global__ __launch_bounds__(256) void prep_gemm(const float* __restrict__ x,
                                                 const float* __restrict__ w,
                                                 float* __restrict__ outf,
                                                 __half* __restrict__ outh) {
    __shared__ float At[8][256];
    const int d = threadIdx.x;
    const int row0 = blockIdx.x * 8;
    for (int rr = 0; rr < 8; ++rr) {
        int r = row0 + rr;
        const float* src;
        if (MODE == 0 || MODE == 3) { int b = r >> 8, l = r & 255; src = x + (size_t)(b * 384 + l) * 256; }
        else if (MODE == 1)         { int t = r >> 5, bb = r & 31; src = x + (size_t)(bb * 384 + 256 + t) * 256; }
        else                        { src = x + (size_t)r * 256; }
        At[rr][d] = src[d];
    }
    __syncthreads();
    float acc[8] = {0.f,0.f,0.f,0.f,0.f,0.f,0.f,0.f};
    for (int k = 0; k < 256; k += 4) {
        float w0 = w[(size_t)(k + 0) * 256 + d];
        float w1 = w[(size_t)(k + 1) * 256 + d];
        float w2 = w[(size_t)(k + 2) * 256 + d];
        float w3 = w[(size_t)(k + 3) * 256 + d];
#pragma unroll
        for (int rr = 0; rr < 8; ++rr) {
            const float4 a = *(const float4*)&At[rr][k];
            float t0 = fmaf(a.x, w0, acc[rr]);
            t0 = fmaf(a.y, w1, t0);
            t0 = fmaf(a.z, w2, t0);
            acc[rr] = fmaf(a.w, w3, t0);
        }
    }
    for (int rr = 0; rr < 8; ++rr) {
        int r = row0 + rr;
        if (MODE == 0)      outh[(size_t)r * 256 + d] = __float2half(acc[rr] * C2X);
        else if (MODE == 1) outf[(size_t)r * 256 + d] = acc[rr] * C2X;
        else                outh[(size_t)r * 256 + d] = __float2half(acc[rr]);
    }
}

__global__ __launch_bounds__(256) void prep_cvt(const float* __restrict__ x,
                                                const float* __restrict__ wt,
                                                __half* __restrict__ prem_h,
                                                __half* __restrict__ wt_h) {
    int i = blockIdx.x * 256 + threadIdx.x;
    float4 v; __half* dst; int e;
    if (i < 524288) {
        e = i * 4; int b = e >> 16;
        v = *(const float4*)(x + (size_t)e + (size_t)b * 32768);
        dst = prem_h + e;
    } else if (i < 540672) {
        e = (i - 524288) * 4;
        v = *(const float4*)(wt + e);
        dst = wt_h + e;
    } else return;
    __half h[4] = {__float2half(v.x),__float2half(v.y),__float2half(v.z),__float2half(v.w)};
    *(uint2*)dst = *(const uint2*)h;
}

// ---------------- exchange primitives ----------------
__device__ __forceinline__ u64 agent_load64(const u64* p) {
    return __hip_atomic_load(p, __ATOMIC_RELAXED, __HIP_MEMORY_SCOPE_AGENT);
}
__device__ __forceinline__ void agent_store64(u64* p, u64 v) {
    __hip_atomic_store(p, v, __ATOMIC_RELAXED, __HIP_MEMORY_SCOPE_AGENT);
}
// L1-bypass, L2-lookup load (same-XCD coherent fast path)
__device__ __forceinline__ u64 sc0_load64(const u64* p) {
    u64 v;
    asm volatile("global_load_dwordx2 %0, %1, off sc0\n\t"
                 "s_waitcnt vmcnt(0)"
                 : "=v"(v) : "v"(p) : "memory");
    return v;
}
// batched 8-way sc0 load, stride 256 u64 (2048 B)
__device__ __forceinline__ void load8_sc0(const u64* p, u64* v) {
    const u64* a0 = p;
    const u64* a2 = p + 512;
    const u64* a4 = p + 1024;
    const u64* a6 = p + 1536;
    u64 z0, z1, z2, z3, z4, z5, z6, z7;
    asm volatile(
        "global_load_dwordx2 %0, %8, off sc0\n\t"
        "global_load_dwordx2 %1, %8, off offset:2048 sc0\n\t"
        "global_load_dwordx2 %2, %9, off sc0\n\t"
        "global_load_dwordx2 %3, %9, off offset:2048 sc0\n\t"
        "global_load_dwordx2 %4, %10, off sc0\n\t"
        "global_load_dwordx2 %5, %10, off offset:2048 sc0\n\t"
        "global_load_dwordx2 %6, %11, off sc0\n\t"
        "global_load_dwordx2 %7, %11, off offset:2048 sc0\n\t"
        "s_waitcnt vmcnt(0)"
        : "=&v"(z0), "=&v"(z1), "=&v"(z2), "=&v"(z3),
          "=&v"(z4), "=&v"(z5), "=&v"(z6), "=&v"(z7)
        : "v"(a0), "v"(a2), "v"(a4), "v"(a6)
        : "memory");
    v[0]=z0; v[1]=z1; v[2]=z2; v[3]=z3; v[4]=z4; v[5]=z5; v[6]=z6; v[7]=z7;
}

// ---------------- main: 8 same-XCD blocks/batch, tagged-u64 exchange ----------------
__global__ __launch_bounds__(512, 1) void wbw_main(
    const __half* __restrict__ wys, const __half* __restrict__ prh,
    const __half* __restrict__ premh, const __half* __restrict__ wth,
    const __half* __restrict__ wtrh, const float* __restrict__ hwh,
    const float* __restrict__ walpha, float* __restrict__ out,
    u64* __restrict__ zp, u64* __restrict__ zps,
    u64* __restrict__ rch, u64* __restrict__ rchs,
    unsigned* __restrict__ ctr)
{
    extern __shared__ char lds[];
    const int tid = threadIdx.x;

    __half* prc    = (__half*)(lds + PRC_OFF);
    __half* wtrc   = (__half*)(lds + WTRC_OFF);
    __half* premc  = (__half*)(lds + PREMC_OFF);
    __half* wtc    = (__half*)(lds + WTC_OFF);
    float*  hwhc   = (float*)(lds + HWHC_OFF);
    float*  s_ch   = (float*)(lds + SCH_OFF);
    float*  wa_ch  = (float*)(lds + WACH_OFF);
    float*  al     = (float*)(lds + AL_OFF);
    float*  rb0    = (float*)(lds + RB0_OFF);
    float*  rb1    = (float*)(lds + RB1_OFF);
    float*  part   = (float*)(lds + PART_OFF);
    float*  red    = (float*)(lds + RED_OFF);

    // ---- bootstrap: group the 8 blocks of a batch onto one XCD ----
    __shared__ int role_sh[2];
    if (tid == 0) {
        unsigned xcd;
        asm volatile("s_getreg_b32 %0, hwreg(HW_REG_XCC_ID)" : "=s"(xcd));
        xcd &= 7u;
        unsigned slot = atomicAdd(&ctr[xcd], 1u);        // 0..31 (1 block/CU forced)
        role_sh[0] = (int)((xcd * 4u + (slot >> 3)) & 31u);
        role_sh[1] = (int)(slot & 7u);
    }
    __syncthreads();
    const int b = role_sh[0], j = role_sh[1];

    // ---- stage the five [256][32] fp16 column-chunk matrices ----
    {
        const int prt = tid & 3;
        for (int it = 0; it < 2; ++it) {
            int row = it * 128 + (tid >> 2);
            size_t g = (size_t)row * 256 + j * 32 + prt * 8;
            unsigned lo = (unsigned)row * 64 + (unsigned)prt * 16;
            *(uint4*)(lds + PRC_OFF   + lo) = *(const uint4*)(prh   + (size_t)b * 65536 + g);
            *(uint4*)(lds + WTRC_OFF  + lo) = *(const uint4*)(wtrh  + g);
            *(uint4*)(lds + PREMC_OFF + lo) = *(const uint4*)(premh + (size_t)b * 65536 + g);
            *(uint4*)(lds + WTC_OFF   + lo) = *(const uint4*)(wth   + g);
            *(uint4*)(lds + WYC_OFF   + lo) = *(const uint4*)(wys   + (size_t)b * 65536 + g);
        }
    }
    for (int it = 0; it < 8; ++it) {
        int idx = it * 512 + tid;
        int tt = idx >> 5, dd = idx & 31;
        hwhc[idx] = hwh[((size_t)tt * 32 + b) * 256 + j * 32 + dd];
    }
    if (tid < 32) wa_ch[tid] = walpha[j * 32 + tid];
    if (tid < 256) { al[tid] = 0.f; rb0[tid] = 0.f; rb1[tid] = 0.f; }
    __syncthreads();

    for (int t = 0; t < 128; ++t) {
        // ---- P1: s-chunk = hwh + C2X*(alpha_{t-1}@P_r + r_{t-2}@W_tr) ----
        {
            const int d = tid & 31, seg = tid >> 5;
            const __half* mat = (seg < 8) ? prc : wtrc;
            const float*  vec = (seg < 8) ? al : ((t & 1) ? rb0 : rb1);   // r_{t-2}
            const int l0 = (seg & 7) * 32;
            float acc = 0.f;
#pragma unroll
            for (int i = 0; i < 32; ++i)
                acc = fmaf(vec[l0 + i], __half2float(mat[(l0 + i) * 32 + d]), acc);
            part[seg * 32 + d] = acc;
        }
        __syncthreads();
        if (tid < 32) {
            float ssum = 0.f;
#pragma unroll
            for (int s2 = 0; s2 < 16; ++s2) ssum += part[s2 * 32 + tid];
            s_ch[tid] = fmaf(ssum, C2X, hwhc[t * 32 + tid]);
        }
        __syncthreads();

        // ---- P2: zpart[l] for all 256 l; even lane stores tagged u64 directly ----
        {
            const int l = tid >> 1, dh = (tid & 1) << 4;
            union { uint4 u[2]; __half h[16]; } W;
            W.u[0] = *(const uint4*)(lds + WYC_OFF + (unsigned)l * 64 + (unsigned)dh * 2);
            W.u[1] = *(const uint4*)(lds + WYC_OFF + (unsigned)l * 64 + (unsigned)dh * 2 + 16);
            float acc = 0.f;
#pragma unroll
            for (int i = 0; i < 16; ++i) {
                float arg = __half2float(W.h[i]) + s_ch[dh + i];
                float u = __builtin_amdgcn_rcpf(__builtin_amdgcn_exp2f(arg) + 1.f);
                acc = fmaf(wa_ch[dh + i], u, acc);
            }
            acc += __shfl_xor(acc, 1, 64);
            if ((tid & 1) == 0) {
                u64 pk = ((u64)(unsigned)(t + 1) << 32) | (u64)__float_as_uint(acc);
                size_t idx = (size_t)(((t & 1) * 32 + b) * 8 + j) * 256 + l;
                zp[idx] = pk;              // primary: write-through L1 -> local L2
                agent_store64(&zps[idx], pk);   // shadow: IF$
            }
        }

        // ---- r-gather: r_{t-1}, tag t, slot t&1 (one tagged u64 per lane) ----
        if (tid < 256) {
            size_t ri = (size_t)((t & 1) * 32 + b) * 256 + tid;
            unsigned expr_ = (unsigned)t;
            u64 rv; int tries = 0;
            for (;;) {
                rv = (tries < 64) ? sc0_load64(&rch[ri]) : agent_load64(&rchs[ri]);
                if (__all((unsigned)(rv >> 32) >= expr_)) break;
                if (++tries > 12) __builtin_amdgcn_s_sleep(2);
            }
            float* rbc = (t & 1) ? rb1 : rb0;
            rbc[tid] = __uint_as_float((unsigned)rv);
        }

        // ---- z-gather: poll 8 tagged partials, tag t+1, slot t&1 ----
        float zz = -1e30f, ee = 0.f;
        if (tid < 256) {
            const u64* zb  = zp  + (size_t)((t & 1) * 32 + b) * 2048 + tid;
            const u64* zbs = zps + (size_t)((t & 1) * 32 + b) * 2048 + tid;
            unsigned expz = (unsigned)(t + 1);
            u64 v[8]; int tries = 0;
            for (;;) {
                if (tries < 64) load8_sc0(zb, v);
                else {
#pragma unroll
                    for (int jj = 0; jj < 8; ++jj) v[jj] = agent_load64(zbs + jj * 256);
                }
                bool ok = true;
#pragma unroll
                for (int jj = 0; jj < 8; ++jj) ok &= ((unsigned)(v[jj] >> 32) >= expz);
                if (__all(ok)) break;
                if (++tries > 12) __builtin_amdgcn_s_sleep(2);
            }
            float zs = 0.f;
#pragma unroll
            for (int jj = 0; jj < 8; ++jj) zs += __uint_as_float((unsigned)v[jj]);
            zz = -2.f * zs;
        }

        // ---- P3: redundant softmax over 256 ----
        {
            float mv = zz;
#pragma unroll
            for (int off = 32; off; off >>= 1) mv = fmaxf(mv, __shfl_xor(mv, off, 64));
            if (tid < 256 && (tid & 63) == 0) red[tid >> 6] = mv;
        }
        __syncthreads();
        if (tid < 256) {
            float M = fmaxf(fmaxf(red[0], red[1]), fmaxf(red[2], red[3]));
            ee = __builtin_amdgcn_exp2f((zz - M) * LOG2E);
            float sv = ee;
#pragma unroll
            for (int off = 32; off; off >>= 1) sv += __shfl_xor(sv, off, 64);
            if ((tid & 63) == 0) red[4 + (tid >> 6)] = sv;
        }
        __syncthreads();
        if (tid < 256) {
            float denom = red[4] + red[5] + red[6] + red[7];
            al[tid] = ee * __builtin_amdgcn_rcpf(denom);
        }
        __syncthreads();

        // ---- P4: r_t-chunk = alpha_t@prem + r_{t-1}@w_t ----
        {
            const int d = tid & 31, seg = tid >> 5;
            const __half* mat = (seg < 8) ? premc : wtc;
            const float*  vec = (seg < 8) ? al : ((t & 1) ? rb1 : rb0);   // r_{t-1}
            const int l0 = (seg & 7) * 32;
            float acc = 0.f;
#pragma unroll
            for (int i = 0; i < 32; ++i)
                acc = fmaf(vec[l0 + i], __half2float(mat[(l0 + i) * 32 + d]), acc);
            part[seg * 32 + d] = acc;
        }
        __syncthreads();
        if (tid < 32) {
            float rv = 0.f;
#pragma unroll
            for (int s2 = 0; s2 < 16; ++s2) rv += part[s2 * 32 + tid];
            out[((size_t)b * 128 + t) * 256 + j * 32 + tid] = rv;
            u64 pk = ((u64)(unsigned)(t + 1) << 32) | (u64)__float_as_uint(rv);
            size_t ri = (size_t)(((t + 1) & 1) * 32 + b) * 256 + j * 32 + tid;
            rch[ri] = pk;                   // primary (local L2)
            agent_store64(&rchs[ri], pk);   // shadow (IF$)
        }
        __syncthreads();
    }
}

extern "C" void kernel_launch(void* const* d_in, const int* in_sizes, int n_in,
                              void* d_out, int out_size, void* d_ws, size_t ws_size,
                              hipStream_t stream) {
    const float* x   = (const float*)d_in[0];
    const float* wy  = (const float*)d_in[1];
    const float* wh  = (const float*)d_in[2];
    const float* wr  = (const float*)d_in[3];
    const float* wal = (const float*)d_in[4];
    const float* wt  = (const float*)d_in[5];

    char* ws = (char*)d_ws;
    __half* wys    = (__half*)(ws + WYS_OFF);
    __half* prh    = (__half*)(ws + PR_OFF);
    __half* premh  = (__half*)(ws + PREMH_OFF);
    float*  hwh    = (float*)(ws + HWH_OFF);
    __half* wth    = (__half*)(ws + WTH_OFF);
    __half* wtrh   = (__half*)(ws + WTR_OFF);
    u64*    zp     = (u64*)(ws + ZP_OFF);
    u64*    zps    = (u64*)(ws + ZPS_OFF);
    u64*    rch    = (u64*)(ws + RCH_OFF);
    u64*    rchs   = (u64*)(ws + RCHS_OFF);
    unsigned* ctr  = (unsigned*)(ws + CTR_OFF);

    hipFuncSetAttribute((const void*)wbw_main,
                        hipFuncAttributeMaxDynamicSharedMemorySize, (int)LDS_TOTAL);

    prep_gemm<0><<<1024, 256, 0, stream>>>(x,  wy, nullptr, wys);
    prep_gemm<1><<<512,  256, 0, stream>>>(x,  wh, hwh, nullptr);
    prep_gemm<3><<<1024, 256, 0, stream>>>(x,  wr, nullptr, prh);
    prep_gemm<2><<<32,   256, 0, stream>>>(wt, wr, nullptr, wtrh);
    prep_cvt<<<2112, 256, 0, stream>>>(x, wt, premh, wth);
    hipMemsetAsync(ws + ZP_OFF, 0, MEMSET_SZ, stream);

    wbw_main<<<256, 512, LDS_TOTAL, stream>>>(wys, prh, premh, wth, wtrh, hwh,
                                              wal, (float*)d_out, zp, zps, rch, rchs, ctr);
}

// Round 5
// 550.085 us; speedup vs baseline: 4.0807x; 4.0807x over previous
//
#include <hip/hip_runtime.h>
#include <hip/hip_fp16.h>

typedef unsigned long long u64;

#define C2X 2.8853900817779268f   // 2*log2(e)
#define LOG2E 1.4426950408889634f

// ---------------- workspace layout (bytes) ----------------
#define WYS_OFF   0u          // half [32][256][256]  WY pre-scaled by 2log2e
#define PR_OFF    4194304u    // half [32][256][256]  P_r = prem @ w_r
#define PREMH_OFF 8388608u    // half [32][256][256]  premise fp16
#define HWH_OFF   12582912u   // f32  [128][32][256]  (h@w_h)*2log2e
#define WTH_OFF   16777216u   // half [256][256]      w_t
#define WTR_OFF   16908288u   // half [256][256]      W_tr = w_t @ w_r
#define ZP_OFF    17039360u   // u64 [2][32][8][256]  tagged z-partials (1MB)
#define RCH_OFF   18087936u   // u64 [2][32][256]     tagged r-chunks (128KB)
#define MEMSET_SZ 1179648u    // zp + rch

// ---------------- LDS layout (bytes) ----------------
#define PRC_OFF   0u        // [256][32] half  P_r chunk        (mats contiguous!)
#define WTRC_OFF  16384u    // [256][32] half  W_tr chunk
#define PREMC_OFF 32768u    // [256][32] half  prem chunk
#define WTC_OFF   49152u    // [256][32] half  w_t chunk
#define WYC_OFF   65536u    // [256][32] half  WY chunk (prescaled)
#define HWHC_OFF  81920u    // [128][32] f32
#define SCH_OFF   98304u    // 32 f32  s chunk (prescaled)
#define WACH_OFF  98432u    // 32 f32  w_alpha chunk (prescaled by -2*LOG2E)
#define AL_OFF    98560u    // 256 f32 alpha
#define RB0_OFF   99584u    // 256 f32 r buffer 0
#define RB1_OFF   100608u   // 256 f32 r buffer 1
#define PART_OFF  101632u   // [32][32] f32 (rows 0-15 s-parts, 16-31 r-parts)
#define RED_OFF   105728u   // 16 f32
#define LDS_TOTAL 105792u   // >80KB => 1 block/CU => all 256 blocks co-resident

// ---------------- prep: GEMMs ----------------
// MODE 0: WY rows (b,l) -> half(acc*C2X)
// MODE 1: HWh rows (t,b) -> f32(acc*C2X)
// MODE 2: generic rows (W_tr: x=w_t) -> half(acc)
// MODE 3: P_r rows (b,l) -> half(acc)
template<int MODE>
__global__ __launch_bounds__(256) void prep_gemm(const float* __restrict__ x,
                                                 const float* __restrict__ w,
                                                 float* __restrict__ outf,
                                                 __half* __restrict__ outh) {
    __shared__ float At[8][256];
    const int d = threadIdx.x;
    const int row0 = blockIdx.x * 8;
    for (int rr = 0; rr < 8; ++rr) {
        int r = row0 + rr;
        const float* src;
        if (MODE == 0 || MODE == 3) { int b = r >> 8, l = r & 255; src = x + (size_t)(b * 384 + l) * 256; }
        else if (MODE == 1)         { int t = r >> 5, bb = r & 31; src = x + (size_t)(bb * 384 + 256 + t) * 256; }
        else                        { src = x + (size_t)r * 256; }
        At[rr][d] = src[d];
    }
    __syncthreads();
    float acc[8] = {0.f,0.f,0.f,0.f,0.f,0.f,0.f,0.f};
    for (int k = 0; k < 256; k += 4) {
        float w0 = w[(size_t)(k + 0) * 256 + d];
        float w1 = w[(size_t)(k + 1) * 256 + d];
        float w2 = w[(size_t)(k + 2) * 256 + d];
        float w3 = w[(size_t)(k + 3) * 256 + d];
#pragma unroll
        for (int rr = 0; rr < 8; ++rr) {
            const float4 a = *(const float4*)&At[rr][k];
            float t0 = fmaf(a.x, w0, acc[rr]);
            t0 = fmaf(a.y, w1, t0);
            t0 = fmaf(a.z, w2, t0);
            acc[rr] = fmaf(a.w, w3, t0);
        }
    }
    for (int rr = 0; rr < 8; ++rr) {
        int r = row0 + rr;
        if (MODE == 0)      outh[(size_t)r * 256 + d] = __float2half(acc[rr] * C2X);
        else if (MODE == 1) outf[(size_t)r * 256 + d] = acc[rr] * C2X;
        else                outh[(size_t)r * 256 + d] = __float2half(acc[rr]);
    }
}

__global__ __launch_bounds__(256) void prep_cvt(const float* __restrict__ x,
                                                const float* __restrict__ wt,
                                                __half* __restrict__ prem_h,
                                                __half* __restrict__ wt_h) {
    int i = blockIdx.x * 256 + threadIdx.x;
    float4 v; __half* dst; int e;
    if (i < 524288) {
        e = i * 4; int b = e >> 16;
        v = *(const float4*)(x + (size_t)e + (size_t)b * 32768);
        dst = prem_h + e;
    } else if (i < 540672) {
        e = (i - 524288) * 4;
        v = *(const float4*)(wt + e);
        dst = wt_h + e;
    } else return;
    __half h[4] = {__float2half(v.x),__float2half(v.y),__float2half(v.z),__float2half(v.w)};
    *(uint2*)dst = *(const uint2*)h;
}

// ---------------- agent-scope helpers (IF$-coherent, proven in R3) ----------------
__device__ __forceinline__ u64 agent_load64(const u64* p) {
    return __hip_atomic_load(p, __ATOMIC_RELAXED, __HIP_MEMORY_SCOPE_AGENT);
}
__device__ __forceinline__ void agent_store64(u64* p, u64 v) {
    __hip_atomic_store(p, v, __ATOMIC_RELAXED, __HIP_MEMORY_SCOPE_AGENT);
}

// ---------------- main: 8 blocks/batch, tagged single-exchange pipeline ----------------
__global__ __launch_bounds__(512, 1) void wbw_main(
    const __half* __restrict__ wys, const __half* __restrict__ prh,
    const __half* __restrict__ premh, const __half* __restrict__ wth,
    const __half* __restrict__ wtrh, const float* __restrict__ hwh,
    const float* __restrict__ walpha, float* __restrict__ out,
    u64* __restrict__ zp, u64* __restrict__ rch)
{
    extern __shared__ char lds[];
    const int tid = threadIdx.x;
    const int b = blockIdx.x >> 3, j = blockIdx.x & 7;

    float*  hwhc   = (float*)(lds + HWHC_OFF);
    float*  s_ch   = (float*)(lds + SCH_OFF);
    float*  wa_ch  = (float*)(lds + WACH_OFF);
    float*  al     = (float*)(lds + AL_OFF);
    float*  rb0    = (float*)(lds + RB0_OFF);
    float*  rb1    = (float*)(lds + RB1_OFF);
    float*  part   = (float*)(lds + PART_OFF);
    float*  red    = (float*)(lds + RED_OFF);

    // ---- stage the five [256][32] fp16 column-chunk matrices ----
    {
        const int prt = tid & 3;
        for (int it = 0; it < 2; ++it) {
            int row = it * 128 + (tid >> 2);
            size_t g = (size_t)row * 256 + j * 32 + prt * 8;
            unsigned lo = (unsigned)row * 64 + (unsigned)prt * 16;
            *(uint4*)(lds + PRC_OFF   + lo) = *(const uint4*)(prh   + (size_t)b * 65536 + g);
            *(uint4*)(lds + WTRC_OFF  + lo) = *(const uint4*)(wtrh  + g);
            *(uint4*)(lds + PREMC_OFF + lo) = *(const uint4*)(premh + (size_t)b * 65536 + g);
            *(uint4*)(lds + WTC_OFF   + lo) = *(const uint4*)(wth   + g);
            *(uint4*)(lds + WYC_OFF   + lo) = *(const uint4*)(wys   + (size_t)b * 65536 + g);
        }
    }
    for (int it = 0; it < 8; ++it) {
        int idx = it * 512 + tid;
        int tt = idx >> 5, dd = idx & 31;
        hwhc[idx] = hwh[((size_t)tt * 32 + b) * 256 + j * 32 + dd];
    }
    if (tid < 32) wa_ch[tid] = walpha[j * 32 + tid] * (-2.0f * LOG2E);
    if (tid < 256) { al[tid] = 0.f; rb0[tid] = 0.f; rb1[tid] = 0.f; }
    __syncthreads();

    for (int t = 0; t <= 128; ++t) {
        // ---- fused GEMV: s_t partials (P_r|W_tr) AND r_{t-1} partials (prem|w_t)
        //      both driven by the shared vector pair (alpha_{t-1}, r_{t-2}) ----
        {
            const int seg = tid >> 4;            // 0..31
            const int d0  = (tid & 15) * 2;
            const int s8  = seg & 7;
            const float* vec = (seg & 8) ? ((t & 1) ? rb0 : rb1) : al;   // r_{t-2} or alpha
            const __half* mat = (const __half*)(lds + PRC_OFF + (size_t)(seg >> 3) * 16384u);
            float ax = 0.f, ay = 0.f;
#pragma unroll
            for (int i = 0; i < 32; ++i) {
                int l = s8 + i * 8;              // interleaved-l: 2-way LDS aliasing = free
                float v = vec[l];
                float2 mf = __half22float2(*(const __half2*)&mat[l * 32 + d0]);
                ax = fmaf(v, mf.x, ax);
                ay = fmaf(v, mf.y, ay);
            }
            part[seg * 32 + d0]     = ax;
            part[seg * 32 + d0 + 1] = ay;
        }
        __syncthreads();

        // ---- reduce: s-chunk (threads 0-31) ; r-chunk + publish + out (threads 32-63) ----
        if (tid < 32) {
            if (t < 128) {
                float ss = 0.f;
#pragma unroll
                for (int k = 0; k < 16; ++k) ss += part[k * 32 + tid];
                s_ch[tid] = fmaf(ss, C2X, hwhc[t * 32 + tid]);
            }
        } else if (tid < 64) {
            const int d = tid - 32;
            float rv = 0.f;
#pragma unroll
            for (int k = 16; k < 32; ++k) rv += part[k * 32 + d];
            if (t >= 1) {
                out[((size_t)b * 128 + (t - 1)) * 256 + j * 32 + d] = rv;
                if (t < 128) {
                    u64 pk = ((u64)(unsigned)t << 32) | (u64)__float_as_uint(rv);
                    agent_store64(&rch[(size_t)((t & 1) * 32 + b) * 256 + j * 32 + d], pk);
                }
            }
        }
        __syncthreads();
        if (t == 128) break;

        // ---- P2: z-partials (16 exp per thread), publish tagged ----
        {
            const int l = tid >> 1, dh = (tid & 1) << 4;
            union { uint4 u[2]; __half h[16]; } W;
            W.u[0] = *(const uint4*)(lds + WYC_OFF + (unsigned)l * 64 + (unsigned)dh * 2);
            W.u[1] = *(const uint4*)(lds + WYC_OFF + (unsigned)l * 64 + (unsigned)dh * 2 + 16);
            float acc = 0.f;
#pragma unroll
            for (int i = 0; i < 16; ++i) {
                float arg = __half2float(W.h[i]) + s_ch[dh + i];
                float u = __builtin_amdgcn_rcpf(__builtin_amdgcn_exp2f(arg) + 1.f);
                acc = fmaf(wa_ch[dh + i], u, acc);
            }
            acc += __shfl_xor(acc, 1, 64);
            if ((tid & 1) == 0) {
                u64 pk = ((u64)(unsigned)(t + 1) << 32) | (u64)__float_as_uint(acc);
                agent_store64(&zp[(size_t)(((t & 1) * 32 + b) * 8 + j) * 256 + l], pk);
            }
        }

        // ---- z-poll + exp + wave-sum; r-poll overlapped before barrier ----
        float ee = 0.f;
        if (tid < 256) {
            const u64* zb = zp + (size_t)((t & 1) * 32 + b) * 2048 + tid;
            u64 v0,v1,v2,v3,v4,v5,v6,v7; int tries = 0;
            for (;;) {
                v0 = agent_load64(zb);         v1 = agent_load64(zb + 256);
                v2 = agent_load64(zb + 512);   v3 = agent_load64(zb + 768);
                v4 = agent_load64(zb + 1024);  v5 = agent_load64(zb + 1280);
                v6 = agent_load64(zb + 1536);  v7 = agent_load64(zb + 1792);
                bool ok = ((unsigned)(v0 >> 32) > (unsigned)t) & ((unsigned)(v1 >> 32) > (unsigned)t)
                        & ((unsigned)(v2 >> 32) > (unsigned)t) & ((unsigned)(v3 >> 32) > (unsigned)t)
                        & ((unsigned)(v4 >> 32) > (unsigned)t) & ((unsigned)(v5 >> 32) > (unsigned)t)
                        & ((unsigned)(v6 >> 32) > (unsigned)t) & ((unsigned)(v7 >> 32) > (unsigned)t);
                if (__all(ok)) break;
                if (++tries > 2) __builtin_amdgcn_s_sleep(1);
            }
            float zs = __uint_as_float((unsigned)v0) + __uint_as_float((unsigned)v1)
                     + __uint_as_float((unsigned)v2) + __uint_as_float((unsigned)v3)
                     + __uint_as_float((unsigned)v4) + __uint_as_float((unsigned)v5)
                     + __uint_as_float((unsigned)v6) + __uint_as_float((unsigned)v7);
            ee = __builtin_amdgcn_exp2f(zs);        // no max-pass: |zs| <= ~37, fp32-safe
            float sv = ee;
#pragma unroll
            for (int off = 32; off; off >>= 1) sv += __shfl_xor(sv, off, 64);
            if ((tid & 63) == 0) red[tid >> 6] = sv;

            // r_{t-1} gather (published early this step; usually instant)
            const u64* rp = &rch[(size_t)((t & 1) * 32 + b) * 256 + tid];
            u64 rv;
            for (;;) {
                rv = agent_load64(rp);
                if (__all((unsigned)(rv >> 32) >= (unsigned)t)) break;
                __builtin_amdgcn_s_sleep(1);
            }
            float* rbN = (t & 1) ? rb1 : rb0;       // becomes r_{t-2} view at step t+1
            rbN[tid] = __uint_as_float((unsigned)rv);
        }
        __syncthreads();
        if (tid < 256) {
            float denom = red[0] + red[1] + red[2] + red[3];
            al[tid] = ee * __builtin_amdgcn_rcpf(denom);
        }
        __syncthreads();
    }
}

extern "C" void kernel_launch(void* const* d_in, const int* in_sizes, int n_in,
                              void* d_out, int out_size, void* d_ws, size_t ws_size,
                              hipStream_t stream) {
    const float* x   = (const float*)d_in[0];
    const float* wy  = (const float*)d_in[1];
    const float* wh  = (const float*)d_in[2];
    const float* wr  = (const float*)d_in[3];
    const float* wal = (const float*)d_in[4];
    const float* wt  = (const float*)d_in[5];

    char* ws = (char*)d_ws;
    __half* wys    = (__half*)(ws + WYS_OFF);
    __half* prh    = (__half*)(ws + PR_OFF);
    __half* premh  = (__half*)(ws + PREMH_OFF);
    float*  hwh    = (float*)(ws + HWH_OFF);
    __half* wth    = (__half*)(ws + WTH_OFF);
    __half* wtrh   = (__half*)(ws + WTR_OFF);
    u64*    zp     = (u64*)(ws + ZP_OFF);
    u64*    rch    = (u64*)(ws + RCH_OFF);

    hipFuncSetAttribute((const void*)wbw_main,
                        hipFuncAttributeMaxDynamicSharedMemorySize, (int)LDS_TOTAL);

    prep_gemm<0><<<1024, 256, 0, stream>>>(x,  wy, nullptr, wys);
    prep_gemm<1><<<512,  256, 0, stream>>>(x,  wh, hwh, nullptr);
    prep_gemm<3><<<1024, 256, 0, stream>>>(x,  wr, nullptr, prh);
    prep_gemm<2><<<32,   256, 0, stream>>>(wt, wr, nullptr, wtrh);
    prep_cvt<<<2112, 256, 0, stream>>>(x, wt, premh, wth);
    hipMemsetAsync(ws + ZP_OFF, 0, MEMSET_SZ, stream);

    wbw_main<<<256, 512, LDS_TOTAL, stream>>>(wys, prh, premh, wth, wtrh, hwh,
                                              wal, (float*)d_out, zp, rch);
}

// Round 7
// 448.834 us; speedup vs baseline: 5.0013x; 1.2256x over previous
//
#include <hip/hip_runtime.h>
#include <hip/hip_fp16.h>

typedef unsigned long long u64;

#define C2X 2.8853900817779268f   // 2*log2(e)
#define LOG2E 1.4426950408889634f

// ---------------- workspace layout (bytes) ----------------
#define WYS_OFF   0u          // half [32][256][256]  WY pre-scaled by 2log2e
#define PR_OFF    4194304u    // half [32][256][256]  P_r = prem @ w_r
#define PREMH_OFF 8388608u    // half [32][256][256]  premise fp16
#define HWH_OFF   12582912u   // f32  [128][32][256]  (h@w_h)*2log2e
#define WTH_OFF   16777216u   // half [256][256]      w_t
#define WTR_OFF   16908288u   // half [256][256]      W_tr = w_t @ w_r
#define ZP_OFF    17039360u   // u64 [2][32][8][256]  tagged z-partials (1MB)
#define RCH_OFF   18087936u   // u64 [2][32][256]     tagged r-chunks (128KB)
#define MEMSET_SZ 1179648u    // zp + rch

// ---------------- LDS layout (bytes) ----------------
#define PRC_OFF   0u        // [256][32] half  P_r chunk
#define WTRC_OFF  16384u    // [256][32] half  W_tr chunk
#define PREMC_OFF 32768u    // [256][32] half  prem chunk
#define WTC_OFF   49152u    // [256][32] half  w_t chunk
#define WYC_OFF   65536u    // [256][32] half  WY chunk (prescaled)
#define HWHC_OFF  81920u    // [128][32] f32
#define SCH_OFF   98304u    // 32 f32  s chunk (prescaled)
#define WACH_OFF  98432u    // 32 f32  w_alpha chunk (prescaled by -2*LOG2E)
#define AL_OFF    98560u    // 256 f32 e (unnormalized alpha)
#define RB_OFF    99584u    // 256 f32 r (single buffer)
#define PART_OFF  100608u   // [32][33] f32 padded (4224 B)
#define RED_OFF   104832u   // 8 f32 (parity-double-buffered denom partials)
#define LDS_TOTAL 104864u   // >80KB => 1 block/CU => all 256 blocks co-resident

// ---------------- prep: everything in ONE launch ----------------
// blk <1024          : fused WY & P_r rows (b,l)
// blk <1536          : HWh rows (t,b) -> f32*C2X
// blk <1568          : W_tr = w_t @ w_r rows
// blk 1568..3679     : fp16 cvt of premise & w_t (2112 blocks = 540672 quads)
__global__ __launch_bounds__(256) void prep_all(const float* __restrict__ x,
                                                const float* __restrict__ wy,
                                                const float* __restrict__ wh,
                                                const float* __restrict__ wr,
                                                const float* __restrict__ wt,
                                                __half* __restrict__ wys,
                                                __half* __restrict__ prh,
                                                float* __restrict__ hwh,
                                                __half* __restrict__ wtrh,
                                                __half* __restrict__ premh,
                                                __half* __restrict__ wth) {
    const int blk = blockIdx.x;
    if (blk >= 1568) {
        int i = (blk - 1568) * 256 + threadIdx.x;   // quad index
        float4 v; __half* dst; int e;
        if (i < 524288) {                           // 524288 quads = 2097152 halves
            e = i * 4; int b = e >> 16;
            v = *(const float4*)(x + (size_t)e + (size_t)b * 32768);
            dst = premh + e;
        } else if (i < 540672) {                    // 16384 quads for w_t
            e = (i - 524288) * 4;
            v = *(const float4*)(wt + e);
            dst = wth + e;
        } else return;
        __half h[4] = {__float2half(v.x),__float2half(v.y),__float2half(v.z),__float2half(v.w)};
        *(uint2*)dst = *(const uint2*)h;
        return;
    }
    __shared__ float At[8][256];
    const int d = threadIdx.x;
    int mode, row0;
    if (blk < 1024)      { mode = 0; row0 = blk * 8; }
    else if (blk < 1536) { mode = 1; row0 = (blk - 1024) * 8; }
    else                 { mode = 2; row0 = (blk - 1536) * 8; }
    for (int rr = 0; rr < 8; ++rr) {
        int r = row0 + rr;
        const float* src;
        if (mode == 0)      { int b = r >> 8, l = r & 255; src = x + (size_t)(b * 384 + l) * 256; }
        else if (mode == 1) { int tt = r >> 5, bb = r & 31; src = x + (size_t)(bb * 384 + 256 + tt) * 256; }
        else                { src = wt + (size_t)r * 256; }
        At[rr][d] = src[d];
    }
    __syncthreads();
    if (mode == 0) {
        float accy[8] = {0,0,0,0,0,0,0,0}, accr[8] = {0,0,0,0,0,0,0,0};
        for (int k = 0; k < 256; k += 2) {
            float y0 = wy[(size_t)k * 256 + d], y1 = wy[(size_t)(k + 1) * 256 + d];
            float r0 = wr[(size_t)k * 256 + d], r1 = wr[(size_t)(k + 1) * 256 + d];
#pragma unroll
            for (int rr = 0; rr < 8; ++rr) {
                float2 a = *(const float2*)&At[rr][k];
                accy[rr] = fmaf(a.x, y0, accy[rr]); accy[rr] = fmaf(a.y, y1, accy[rr]);
                accr[rr] = fmaf(a.x, r0, accr[rr]); accr[rr] = fmaf(a.y, r1, accr[rr]);
            }
        }
        for (int rr = 0; rr < 8; ++rr) {
            int r = row0 + rr;
            wys[(size_t)r * 256 + d] = __float2half(accy[rr] * C2X);
            prh[(size_t)r * 256 + d] = __float2half(accr[rr]);
        }
    } else {
        const float* w = (mode == 1) ? wh : wr;
        float acc[8] = {0,0,0,0,0,0,0,0};
        for (int k = 0; k < 256; k += 4) {
            float w0 = w[(size_t)k * 256 + d], w1 = w[(size_t)(k+1) * 256 + d];
            float w2 = w[(size_t)(k+2) * 256 + d], w3 = w[(size_t)(k+3) * 256 + d];
#pragma unroll
            for (int rr = 0; rr < 8; ++rr) {
                float4 a = *(const float4*)&At[rr][k];
                float t0 = fmaf(a.x, w0, acc[rr]);
                t0 = fmaf(a.y, w1, t0);
                t0 = fmaf(a.z, w2, t0);
                acc[rr] = fmaf(a.w, w3, t0);
            }
        }
        for (int rr = 0; rr < 8; ++rr) {
            int r = row0 + rr;
            if (mode == 1) hwh[(size_t)r * 256 + d] = acc[rr] * C2X;
            else           wtrh[(size_t)r * 256 + d] = __float2half(acc[rr]);
        }
    }
}

// ---------------- agent-scope helpers (IF$-coherent) ----------------
__device__ __forceinline__ u64 agent_load64(const u64* p) {
    return __hip_atomic_load(p, __ATOMIC_RELAXED, __HIP_MEMORY_SCOPE_AGENT);
}
__device__ __forceinline__ void agent_store64(u64* p, u64 v) {
    __hip_atomic_store(p, v, __ATOMIC_RELAXED, __HIP_MEMORY_SCOPE_AGENT);
}

// ---------------- main: 8 blocks/batch, poll-window-hidden r-work ----------------
__global__ __launch_bounds__(512, 1) void wbw_main(
    const __half* __restrict__ wys, const __half* __restrict__ prh,
    const __half* __restrict__ premh, const __half* __restrict__ wth,
    const __half* __restrict__ wtrh, const float* __restrict__ hwh,
    const float* __restrict__ walpha, float* __restrict__ out,
    u64* __restrict__ zp, u64* __restrict__ rch)
{
    extern __shared__ char lds[];
    const int tid = threadIdx.x;
    const int b = blockIdx.x >> 3, j = blockIdx.x & 7;

    float* hwhc  = (float*)(lds + HWHC_OFF);
    float* s_ch  = (float*)(lds + SCH_OFF);
    float* wa_ch = (float*)(lds + WACH_OFF);
    float* al    = (float*)(lds + AL_OFF);    // unnormalized e
    float* rb    = (float*)(lds + RB_OFF);
    float* part  = (float*)(lds + PART_OFF);  // [32][33]
    float* red   = (float*)(lds + RED_OFF);   // [2][4]

    // ---- stage the five [256][32] fp16 column-chunk matrices ----
    {
        const int prt = tid & 3;
        for (int it = 0; it < 2; ++it) {
            int row = it * 128 + (tid >> 2);
            size_t g = (size_t)row * 256 + j * 32 + prt * 8;
            unsigned lo = (unsigned)row * 64 + (unsigned)prt * 16;
            *(uint4*)(lds + PRC_OFF   + lo) = *(const uint4*)(prh   + (size_t)b * 65536 + g);
            *(uint4*)(lds + WTRC_OFF  + lo) = *(const uint4*)(wtrh  + g);
            *(uint4*)(lds + PREMC_OFF + lo) = *(const uint4*)(premh + (size_t)b * 65536 + g);
            *(uint4*)(lds + WTC_OFF   + lo) = *(const uint4*)(wth   + g);
            *(uint4*)(lds + WYC_OFF   + lo) = *(const uint4*)(wys   + (size_t)b * 65536 + g);
        }
    }
    for (int it = 0; it < 8; ++it) {
        int idx = it * 512 + tid;
        int tt = idx >> 5, dd = idx & 31;
        hwhc[idx] = hwh[((size_t)tt * 32 + b) * 256 + j * 32 + dd];
    }
    if (tid < 32) wa_ch[tid] = walpha[j * 32 + tid] * (-2.0f * LOG2E);
    if (tid < 256) { al[tid] = 0.f; rb[tid] = 0.f; }
    if (tid < 8)   red[tid] = (tid == 0 || tid == 4) ? 1.f : 0.f;
    __syncthreads();

    for (int t = 0; t <= 128; ++t) {
        const int par = t & 1;
        if (t < 128) {
            // ---- P1: s-GEMV  rows0-15: e@P_r  rows16-31: rb@W_tr ----
            {
                const int half_ = tid >> 8;
                const int s16 = (tid >> 4) & 15;
                const int d0 = (tid & 15) * 2;
                const __half* mat = (const __half*)(lds + (half_ ? WTRC_OFF : PRC_OFF));
                const float* vec = half_ ? rb : al;
                float ax = 0.f, ay = 0.f;
#pragma unroll
                for (int i = 0; i < 16; ++i) {
                    int l = s16 + i * 16;
                    float v = vec[l];
                    float2 mf = __half22float2(*(const __half2*)&mat[l * 32 + d0]);
                    ax = fmaf(v, mf.x, ax); ay = fmaf(v, mf.y, ay);
                }
                const int row = half_ * 16 + s16;
                part[row * 33 + d0] = ax; part[row * 33 + d0 + 1] = ay;
            }
            __syncthreads();
            // ---- P1b: s-reduce with deferred 1/Den on the e-part ----
            if (tid < 32) {
                const float* rd = red + (par ^ 1) * 4;
                float rD = __builtin_amdgcn_rcpf(rd[0] + rd[1] + rd[2] + rd[3]);
                float se = 0.f, sr = 0.f;
#pragma unroll
                for (int s2 = 0; s2 < 16; ++s2) {
                    se += part[s2 * 33 + tid];
                    sr += part[(16 + s2) * 33 + tid];
                }
                s_ch[tid] = fmaf(fmaf(se, rD, sr), C2X, hwhc[t * 32 + tid]);
            }
            __syncthreads();
            // ---- P2: z-partials + tagged publish ----
            {
                const int l = tid >> 1, dh = (tid & 1) << 4;
                union { uint4 u[2]; __half h[16]; } W;
                W.u[0] = *(const uint4*)(lds + WYC_OFF + (unsigned)l * 64 + (unsigned)dh * 2);
                W.u[1] = *(const uint4*)(lds + WYC_OFF + (unsigned)l * 64 + (unsigned)dh * 2 + 16);
                float acc = 0.f;
#pragma unroll
                for (int i = 0; i < 16; ++i) {
                    float arg = __half2float(W.h[i]) + s_ch[dh + i];
                    float u = __builtin_amdgcn_rcpf(__builtin_amdgcn_exp2f(arg) + 1.f);
                    acc = fmaf(wa_ch[dh + i], u, acc);
                }
                acc += __shfl_xor(acc, 1, 64);
                if ((tid & 1) == 0) {
                    u64 pk = ((u64)(unsigned)(t + 1) << 32) | (u64)__float_as_uint(acc);
                    agent_store64(&zp[(size_t)((par * 32 + b) * 8 + j) * 256 + l], pk);
                }
            }
        }
        // ---- P3: r-GEMV (hidden in poll window) rows0-15: e@prem rows16-31: rb@w_t ----
        {
            const int half_ = tid >> 8;
            const int s16 = (tid >> 4) & 15;
            const int d0 = (tid & 15) * 2;
            const __half* mat = (const __half*)(lds + (half_ ? WTC_OFF : PREMC_OFF));
            const float* vec = half_ ? rb : al;
            float ax = 0.f, ay = 0.f;
#pragma unroll
            for (int i = 0; i < 16; ++i) {
                int l = s16 + i * 16;
                float v = vec[l];
                float2 mf = __half22float2(*(const __half2*)&mat[l * 32 + d0]);
                ax = fmaf(v, mf.x, ax); ay = fmaf(v, mf.y, ay);
            }
            const int row = half_ * 16 + s16;
            part[row * 33 + d0] = ax; part[row * 33 + d0 + 1] = ay;
        }
        __syncthreads();
        // ---- P3b (wave7 lanes 448-479): r-reduce + out + publish ∥ P4 (waves0-3): polls ----
        if (tid >= 448 && tid < 480) {
            const int d = tid - 448;
            const float* rd = red + (par ^ 1) * 4;
            float rD = __builtin_amdgcn_rcpf(rd[0] + rd[1] + rd[2] + rd[3]);
            float se = 0.f, sr = 0.f;
#pragma unroll
            for (int s2 = 0; s2 < 16; ++s2) {
                se += part[s2 * 33 + d];
                sr += part[(16 + s2) * 33 + d];
            }
            float rv = fmaf(se, rD, sr);
            if (t >= 1) out[((size_t)b * 128 + (t - 1)) * 256 + j * 32 + d] = rv;
            if (t < 128) {
                u64 pk = ((u64)(unsigned)t << 32) | (u64)__float_as_uint(rv);
                agent_store64(&rch[(size_t)(par * 32 + b) * 256 + j * 32 + d], pk);
            }
        } else if (tid < 256 && t < 128) {
            // z-poll (tag > t)
            const u64* zb = zp + (size_t)(par * 32 + b) * 2048 + tid;
            u64 v0,v1,v2,v3,v4,v5,v6,v7; int tries = 0;
            for (;;) {
                v0 = agent_load64(zb);         v1 = agent_load64(zb + 256);
                v2 = agent_load64(zb + 512);   v3 = agent_load64(zb + 768);
                v4 = agent_load64(zb + 1024);  v5 = agent_load64(zb + 1280);
                v6 = agent_load64(zb + 1536);  v7 = agent_load64(zb + 1792);
                bool ok = ((unsigned)(v0 >> 32) > (unsigned)t) & ((unsigned)(v1 >> 32) > (unsigned)t)
                        & ((unsigned)(v2 >> 32) > (unsigned)t) & ((unsigned)(v3 >> 32) > (unsigned)t)
                        & ((unsigned)(v4 >> 32) > (unsigned)t) & ((unsigned)(v5 >> 32) > (unsigned)t)
                        & ((unsigned)(v6 >> 32) > (unsigned)t) & ((unsigned)(v7 >> 32) > (unsigned)t);
                if (__all(ok)) break;
                if (++tries > 2) __builtin_amdgcn_s_sleep(1);
            }
            float zs = __uint_as_float((unsigned)v0) + __uint_as_float((unsigned)v1)
                     + __uint_as_float((unsigned)v2) + __uint_as_float((unsigned)v3)
                     + __uint_as_float((unsigned)v4) + __uint_as_float((unsigned)v5)
                     + __uint_as_float((unsigned)v6) + __uint_as_float((unsigned)v7);
            float ee = __builtin_amdgcn_exp2f(zs);       // |zs| <= ~37, fp32-safe
            float sv = ee;
#pragma unroll
            for (int off = 32; off; off >>= 1) sv += __shfl_xor(sv, off, 64);
            if ((tid & 63) == 0) red[par * 4 + (tid >> 6)] = sv;
            // r-poll (tag >= t)
            const u64* rp = &rch[(size_t)(par * 32 + b) * 256 + tid];
            u64 rv;
            for (;;) {
                rv = agent_load64(rp);
                if (__all((unsigned)(rv >> 32) >= (unsigned)t)) break;
                __builtin_amdgcn_s_sleep(1);
            }
            rb[tid] = __uint_as_float((unsigned)rv);
            al[tid] = ee;
        }
        __syncthreads();
    }
}

extern "C" void kernel_launch(void* const* d_in, const int* in_sizes, int n_in,
                              void* d_out, int out_size, void* d_ws, size_t ws_size,
                              hipStream_t stream) {
    const float* x   = (const float*)d_in[0];
    const float* wy  = (const float*)d_in[1];
    const float* wh  = (const float*)d_in[2];
    const float* wr  = (const float*)d_in[3];
    const float* wal = (const float*)d_in[4];
    const float* wt  = (const float*)d_in[5];

    char* ws = (char*)d_ws;
    __half* wys    = (__half*)(ws + WYS_OFF);
    __half* prh    = (__half*)(ws + PR_OFF);
    __half* premh  = (__half*)(ws + PREMH_OFF);
    float*  hwh    = (float*)(ws + HWH_OFF);
    __half* wth    = (__half*)(ws + WTH_OFF);
    __half* wtrh   = (__half*)(ws + WTR_OFF);
    u64*    zp     = (u64*)(ws + ZP_OFF);
    u64*    rch    = (u64*)(ws + RCH_OFF);

    hipFuncSetAttribute((const void*)wbw_main,
                        hipFuncAttributeMaxDynamicSharedMemorySize, (int)LDS_TOTAL);

    // grid = 1568 GEMM blocks + 2112 cvt blocks (540672 quads / 256) = 3680
    prep_all<<<3680, 256, 0, stream>>>(x, wy, wh, wr, wt, wys, prh, hwh, wtrh, premh, wth);
    hipMemsetAsync(ws + ZP_OFF, 0, MEMSET_SZ, stream);

    wbw_main<<<256, 512, LDS_TOTAL, stream>>>(wys, prh, premh, wth, wtrh, hwh,
                                              wal, (float*)d_out, zp, rch);
}